// Round 10
// baseline (382.885 us; speedup 1.0000x reference)
//
#include <hip/hip_runtime.h>
#include <math.h>

#define N_NODES 100000
#define N_EDGES 1600000
#define D_IN 128
#define HIDDEN 128
#define D_OUT 40
#define EPSN 1e-12f

#define NBUCK 391
#define EPB 4096
#define NPART ((N_EDGES + EPB - 1) / EPB)    // 391
#define PEPB 16384
#define PNPART ((N_EDGES + PEPB - 1) / PEPB) // 98

#define SWZ1_TOTAL (8 * 8 * 4 * 16 * 8)   // 32768
#define SWZ2_TOTAL (4 * 8 * 4 * 16 * 8)   // 16384
#define CASTB ((N_NODES * 16) / 256)      // 6250: fp32 -> bf16 rows
#define F8B ((N_NODES * 32) / 256)        // 12500: fp32 -> fp8 slice arrays
#define SWZB ((SWZ1_TOTAL + SWZ2_TOTAL + 255) / 256)
#define N8 (N_NODES * 8)                  // u32 per x-fp8 slice

typedef __attribute__((ext_vector_type(8))) short short8;
typedef __attribute__((ext_vector_type(4))) float float4v;

static __device__ inline unsigned short f2bf(float f) {
    union { float f; unsigned u; } v; v.f = f;
    unsigned r = v.u + 0x7fffu + ((v.u >> 16) & 1u);
    return (unsigned short)(r >> 16);
}
static __device__ inline float bflo(unsigned u) {
    union { unsigned u; float f; } v; v.u = u << 16;
    return v.f;
}
static __device__ inline float bfhi(unsigned u) {
    union { unsigned u; float f; } v; v.u = u & 0xffff0000u;
    return v.f;
}

// ---- fp8 e4m3 encode (value -> byte), RTNE via scaled fp32 bit arithmetic ----
static __device__ inline unsigned encf8(float x) {
    union { float f; unsigned u; } v; v.f = x * 0x1p-120f;
    unsigned um = v.u & 0x7fffffffu;
    unsigned r = um + 0x7FFFFu + ((um >> 20) & 1u);
    return ((r >> 20) & 0x7fu) | ((v.u >> 24) & 0x80u);
}

// ---- scaled-domain fp8 decode: pair-expand 2 bytes to bf16-format halves.
// bflo/bfhi of the pair give true_value * 2^-120; scale folded in at the end.
#ifdef __has_builtin
#if __has_builtin(__builtin_amdgcn_perm)
#define USE_PERM 1
#endif
#endif
static __device__ inline unsigned pair_lo(unsigned u) {   // bytes 0,1
#ifdef USE_PERM
    unsigned p = __builtin_amdgcn_perm(0u, u, 0x010C000Cu);  // (b1,?,b0,?)
    return (p & 0x80008000u) | ((p & 0x7f007f00u) >> 4);
#else
    return ((u & 0x80u) << 8) | ((u & 0x7fu) << 4) |
           ((u & 0x8000u) << 16) | ((u & 0x7f00u) << 12);
#endif
}
static __device__ inline unsigned pair_hi(unsigned u) {   // bytes 2,3
#ifdef USE_PERM
    unsigned p = __builtin_amdgcn_perm(0u, u, 0x030C020Cu);  // (b3,?,b2,?)
    return (p & 0x80008000u) | ((p & 0x7f007f00u) >> 4);
#else
    return ((u & 0x800000u) >> 8) | ((u & 0x7f0000u) >> 12) |
           (u & 0x80000000u) | ((u & 0x7f000000u) >> 4);
#endif
}
#define ACC4D(U, A0, A1, A2, A3)                                     \
    { unsigned pl_ = pair_lo(U), ph_ = pair_hi(U);                   \
      A0 += bflo(pl_); A1 += bfhi(pl_);                              \
      A2 += bflo(ph_); A3 += bfhi(ph_); }

// ---------------- prep: bhist + bf16 cast + fp8 slice cast + weight swizzles ----------------
__global__ void prep_kernel(const int* __restrict__ dst, int* __restrict__ bucketCount,
                            const float* __restrict__ x, unsigned* __restrict__ xb,
                            unsigned* __restrict__ xs,
                            const float* __restrict__ Wl1, const float* __restrict__ Wr1,
                            const float* __restrict__ Wl2, const float* __restrict__ Wr2,
                            unsigned short* __restrict__ out1, unsigned short* __restrict__ out2) {
    __shared__ int h[NBUCK];
    int b = blockIdx.x, t = threadIdx.x;
    if (b < NPART) {
        for (int i = t; i < NBUCK; i += 256) h[i] = 0;
        __syncthreads();
        int es = b * EPB;
        int ee = min(es + EPB, N_EDGES);
        for (int i = es + t; i < ee; i += 256) atomicAdd(&h[dst[i] >> 8], 1);
        __syncthreads();
        for (int i = t; i < NBUCK; i += 256)
            if (h[i]) atomicAdd(&bucketCount[i], h[i]);
        return;
    }
    b -= NPART;
    if (b < CASTB) {
        int g = b * 256 + t;
        const float4* x4 = (const float4*)x;
        float4 lo = x4[2 * g], hi = x4[2 * g + 1];
        uint4 o;
        o.x = (unsigned)f2bf(lo.x) | ((unsigned)f2bf(lo.y) << 16);
        o.y = (unsigned)f2bf(lo.z) | ((unsigned)f2bf(lo.w) << 16);
        o.z = (unsigned)f2bf(hi.x) | ((unsigned)f2bf(hi.y) << 16);
        o.w = (unsigned)f2bf(hi.z) | ((unsigned)f2bf(hi.w) << 16);
        ((uint4*)xb)[g] = o;
        return;
    }
    b -= CASTB;
    if (b < F8B) {
        int g = b * 256 + t;                 // one dword = 4 fp8 = x cols [4(g&31), +4) of node g>>5
        float4 f = ((const float4*)x)[g];
        int n = g >> 5, c = g & 31;
        int s = c >> 3, d = c & 7;
        xs[s * N8 + n * 8 + d] =
            encf8(f.x) | (encf8(f.y) << 8) | (encf8(f.z) << 16) | (encf8(f.w) << 24);
        return;
    }
    b -= F8B;
    {
        int idx = b * 256 + t;
        if (idx < SWZ1_TOTAL) {
            int j = idx & 7, l15 = (idx >> 3) & 15, quad = (idx >> 7) & 3;
            int rem = idx >> 9;
            int c = rem & 7, kt = rem >> 3;
            int k = kt * 32 + quad * 8 + j;
            int n = c * 16 + l15;
            float val = (k < 128) ? Wl1[k * HIDDEN + n] : Wr1[(k - 128) * HIDDEN + n];
            out1[idx] = f2bf(val);
        } else if (idx < SWZ1_TOTAL + SWZ2_TOTAL) {
            idx -= SWZ1_TOTAL;
            int j = idx & 7, l15 = (idx >> 3) & 15, quad = (idx >> 7) & 3;
            int rem = idx >> 9;
            int c = rem & 7, kt = rem >> 3;
            int k = kt * 32 + quad * 8 + j;
            int n = c * 16 + l15;
            float val = 0.0f;
            if (n < D_OUT) val = Wl2[k * D_OUT + n];
            else if (n >= 64 && n < 64 + D_OUT) val = Wr2[k * D_OUT + (n - 64)];
            out2[idx] = f2bf(val);
        }
    }
}

// ---------------- scan 391 bucket counts ----------------
__global__ void bscan_kernel(const int* __restrict__ bc, int* __restrict__ bstart,
                             int* __restrict__ cursor) {
    __shared__ int s[256];
    int t = threadIdx.x;
    int a = (2 * t < NBUCK) ? bc[2 * t] : 0;
    int b = (2 * t + 1 < NBUCK) ? bc[2 * t + 1] : 0;
    int tp = a + b;
    s[t] = tp;
    __syncthreads();
    for (int off = 1; off < 256; off <<= 1) {
        int tmp = (t >= off) ? s[t - off] : 0;
        __syncthreads();
        s[t] += tmp;
        __syncthreads();
    }
    int texcl = s[t] - tp;
    if (2 * t < NBUCK) { bstart[2 * t] = texcl; cursor[2 * t] = texcl; }
    if (2 * t + 1 < NBUCK) { bstart[2 * t + 1] = texcl + a; cursor[2 * t + 1] = texcl + a; }
    if (t == 255) bstart[NBUCK] = s[255];
}

// ---------------- partition edges into buckets ----------------
__global__ __launch_bounds__(512) void bpart_kernel(
    const int* __restrict__ src, const int* __restrict__ dst,
    int* __restrict__ cursor, unsigned* __restrict__ pairs) {
    __shared__ int h[NBUCK];
    __shared__ int base[NBUCK];
    int t = threadIdx.x;
    for (int i = t; i < NBUCK; i += 512) h[i] = 0;
    __syncthreads();
    int es = blockIdx.x * PEPB;
    int ee = min(es + PEPB, N_EDGES);
    for (int i = es + t; i < ee; i += 512) atomicAdd(&h[dst[i] >> 8], 1);
    __syncthreads();
    for (int i = t; i < NBUCK; i += 512) {
        int c = h[i];
        base[i] = c ? atomicAdd(&cursor[i], c) : 0;
    }
    __syncthreads();
    for (int i = t; i < NBUCK; i += 512) h[i] = 0;
    __syncthreads();
    for (int i = es + t; i < ee; i += 512) {
        int d = dst[i];
        int bk = d >> 8;
        int r = atomicAdd(&h[bk], 1);
        pairs[base[bk] + r] = ((unsigned)src[i] << 8) | (unsigned)(d & 255);
    }
}

// ---------------- per-bucket CSR finalize ----------------
__global__ void csr_kernel(const unsigned* __restrict__ pairs, const int* __restrict__ bstart,
                           int* __restrict__ hist, int* __restrict__ rowStart,
                           int* __restrict__ sortedSrc) {
    __shared__ int cnt[256];
    __shared__ int sc[256];
    __shared__ int cur[256];
    int b = blockIdx.x, t = threadIdx.x;
    int es = bstart[b], ee = bstart[b + 1];
    cnt[t] = 0;
    __syncthreads();
    for (int i = es + t; i < ee; i += 256) atomicAdd(&cnt[pairs[i] & 255], 1);
    __syncthreads();
    int v = cnt[t];
    sc[t] = v;
    __syncthreads();
    for (int off = 1; off < 256; off <<= 1) {
        int tmp = (t >= off) ? sc[t - off] : 0;
        __syncthreads();
        sc[t] += tmp;
        __syncthreads();
    }
    int excl = sc[t] - v;
    int node = (b << 8) + t;
    if (node < N_NODES) {
        hist[node] = v;
        rowStart[node] = es + excl;
    }
    cur[t] = excl;
    __syncthreads();
    for (int i = es + t; i < ee; i += 256) {
        unsigned p = pairs[i];
        int r = atomicAdd(&cur[p & 255], 1);
        sortedSrc[es + r] = (int)(p >> 8);
    }
}

// ---------------- layer-1 slice gather-mean: one wave per node, 32B slice rows ----------------
// 8 lanes (sub) x 4B cover one 32B row-slice; 8 edge-groups (eg).
__global__ void aggs_kernel(const unsigned* __restrict__ xs,  // [N][8] u32, slice-contiguous
                            const int* __restrict__ sortedSrc,
                            const int* __restrict__ rowStart, const int* __restrict__ hist,
                            uint2* __restrict__ meanb, int s) {
    int w = __builtin_amdgcn_readfirstlane((int)(threadIdx.x >> 6));
    int node = blockIdx.x * 4 + w;
    int lane = threadIdx.x & 63;
    int eg = lane >> 3, sub = lane & 7;
    int s0 = __builtin_amdgcn_readfirstlane(rowStart[node]);
    int cnt = __builtin_amdgcn_readfirstlane(hist[node]);
    float a0 = 0.f, a1 = 0.f, a2 = 0.f, a3 = 0.f;
    int i = 0;
    for (; i + 16 <= cnt; i += 16) {
        int sA = sortedSrc[s0 + i + eg];
        int sB = sortedSrc[s0 + i + 8 + eg];
        unsigned uA = xs[sA * 8 + sub];
        unsigned uB = xs[sB * 8 + sub];
        ACC4D(uA, a0, a1, a2, a3)
        ACC4D(uB, a0, a1, a2, a3)
    }
    for (; i + 8 <= cnt; i += 8) {
        int sA = sortedSrc[s0 + i + eg];
        unsigned uA = xs[sA * 8 + sub];
        ACC4D(uA, a0, a1, a2, a3)
    }
    if (eg < cnt - i) {
        int sA = sortedSrc[s0 + i + eg];
        unsigned uA = xs[sA * 8 + sub];
        ACC4D(uA, a0, a1, a2, a3)
    }
    // reduce over eg (lane bits 3..5)
    a0 += __shfl_xor(a0, 8, 64); a0 += __shfl_xor(a0, 16, 64); a0 += __shfl_xor(a0, 32, 64);
    a1 += __shfl_xor(a1, 8, 64); a1 += __shfl_xor(a1, 16, 64); a1 += __shfl_xor(a1, 32, 64);
    a2 += __shfl_xor(a2, 8, 64); a2 += __shfl_xor(a2, 16, 64); a2 += __shfl_xor(a2, 32, 64);
    a3 += __shfl_xor(a3, 8, 64); a3 += __shfl_xor(a3, 16, 64); a3 += __shfl_xor(a3, 32, 64);
    if (eg == 0) {
        float dinv = 0x1p+120f / fmaxf((float)cnt, 1.0f);  // un-scale + mean
        uint2 o;
        o.x = (unsigned)f2bf(a0 * dinv) | ((unsigned)f2bf(a1 * dinv) << 16);
        o.y = (unsigned)f2bf(a2 * dinv) | ((unsigned)f2bf(a3 * dinv) << 16);
        meanb[(size_t)node * 32 + s * 8 + sub] = o;
    }
}

// ---------------- layer-1 GEMM + norm + relu + layer-2 projection ----------------
__global__ __launch_bounds__(256) void gemm1g_kernel(
    const unsigned short* __restrict__ meanb, const unsigned short* __restrict__ xb,
    const short* __restrict__ bswz1, const float* __restrict__ bias1,
    const short* __restrict__ bswz2,
    unsigned char* __restrict__ g_l8, unsigned short* __restrict__ g_r) {
    __shared__ unsigned short hT[4][16][140];
    int tid = threadIdx.x;
    int w = __builtin_amdgcn_readfirstlane(tid >> 6);
    int lane = tid & 63;
    int l15 = lane & 15, quad = lane >> 4;
    int n0 = blockIdx.x * 64;
    int nodeA = n0 + w * 16 + l15;
    if (nodeA >= N_NODES) nodeA = N_NODES - 1;

    float4v acc[8];
#pragma unroll
    for (int c = 0; c < 8; c++) acc[c] = (float4v){0.f, 0.f, 0.f, 0.f};
#pragma unroll
    for (int kt = 0; kt < 8; kt++) {
        const unsigned short* ab = (kt < 4) ? meanb : xb;
        short8 a = *(const short8*)(ab + (size_t)nodeA * 128 + (kt & 3) * 32 + quad * 8);
#pragma unroll
        for (int c = 0; c < 8; c++) {
            short8 b = *(const short8*)(bswz1 + (((kt * 8 + c) * 4 + quad) * 16 + l15) * 8);
            acc[c] = __builtin_amdgcn_mfma_f32_16x16x32_bf16(a, b, acc[c], 0, 0, 0);
        }
    }

    float v[8][4];
    float ss[4] = {0.f, 0.f, 0.f, 0.f};
#pragma unroll
    for (int c = 0; c < 8; c++) {
        float bi = bias1[c * 16 + l15];
#pragma unroll
        for (int r = 0; r < 4; r++) {
            float t = acc[c][r] + bi;
            v[c][r] = t;
            ss[r] += t * t;
        }
    }
#pragma unroll
    for (int r = 0; r < 4; r++)
        for (int off = 1; off < 16; off <<= 1) ss[r] += __shfl_xor(ss[r], off, 64);
#pragma unroll
    for (int r = 0; r < 4; r++) {
        float inv = 1.0f / fmaxf(sqrtf(ss[r]), EPSN);
#pragma unroll
        for (int c = 0; c < 8; c++) {
            hT[w][quad * 4 + r][c * 16 + l15] = f2bf(fmaxf(v[c][r] * inv, 0.0f));
        }
    }

    float4v acc2[8];
#pragma unroll
    for (int c = 0; c < 8; c++) acc2[c] = (float4v){0.f, 0.f, 0.f, 0.f};
#pragma unroll
    for (int kt = 0; kt < 4; kt++) {
        short8 a = *(const short8*)&hT[w][l15][kt * 32 + quad * 8];
#pragma unroll
        for (int c = 0; c < 8; c++) {
            short8 b = *(const short8*)(bswz2 + (((kt * 8 + c) * 4 + quad) * 16 + l15) * 8);
            acc2[c] = __builtin_amdgcn_mfma_f32_16x16x32_bf16(a, b, acc2[c], 0, 0, 0);
        }
    }
#pragma unroll
    for (int r = 0; r < 4; r++) {
        int node = n0 + w * 16 + quad * 4 + r;
        if (node < N_NODES) {
#pragma unroll
            for (int c = 0; c < 4; c++)
                g_l8[(size_t)node * 64 + c * 16 + l15] = (unsigned char)encf8(acc2[c][r]);
#pragma unroll
            for (int c = 4; c < 8; c++)
                g_r[(size_t)node * 64 + (c - 4) * 16 + l15] = f2bf(acc2[c][r]);
        }
    }
}

// ---------------- layer 2 final: 4 nodes/wave, fp8 g_l gather (64B rows) ----------------
// Lane: g = lane>>4 (node), eg = (lane>>2)&3 (edge group), sub = lane&3 (16B of row).
__global__ void fused2f8_kernel(const uint4* __restrict__ gl8, const uint4* __restrict__ grb,
                                const int* __restrict__ sortedSrc,
                                const int* __restrict__ rowStart, const int* __restrict__ hist,
                                const float* __restrict__ bias, float* __restrict__ out) {
    int tid = threadIdx.x;
    int w = __builtin_amdgcn_readfirstlane(tid >> 6);
    int lane = tid & 63;
    int g = lane >> 4, eg = (lane >> 2) & 3, sub = lane & 3;
    int node = blockIdx.x * 16 + w * 4 + g;
    int s0 = rowStart[node];
    int cnt = hist[node];
    float a[16];
#pragma unroll
    for (int j = 0; j < 16; j++) a[j] = 0.f;
    int i = 0;
    for (; i + 8 <= cnt; i += 8) {
        int sA = sortedSrc[s0 + i + eg];
        int sB = sortedSrc[s0 + i + 4 + eg];
        uint4 vA = gl8[(size_t)sA * 4 + sub];
        uint4 vB = gl8[(size_t)sB * 4 + sub];
        ACC4D(vA.x, a[0], a[1], a[2], a[3])
        ACC4D(vA.y, a[4], a[5], a[6], a[7])
        ACC4D(vA.z, a[8], a[9], a[10], a[11])
        ACC4D(vA.w, a[12], a[13], a[14], a[15])
        ACC4D(vB.x, a[0], a[1], a[2], a[3])
        ACC4D(vB.y, a[4], a[5], a[6], a[7])
        ACC4D(vB.z, a[8], a[9], a[10], a[11])
        ACC4D(vB.w, a[12], a[13], a[14], a[15])
    }
    for (; i + 4 <= cnt; i += 4) {
        int sA = sortedSrc[s0 + i + eg];
        uint4 vA = gl8[(size_t)sA * 4 + sub];
        ACC4D(vA.x, a[0], a[1], a[2], a[3])
        ACC4D(vA.y, a[4], a[5], a[6], a[7])
        ACC4D(vA.z, a[8], a[9], a[10], a[11])
        ACC4D(vA.w, a[12], a[13], a[14], a[15])
    }
    if (eg < cnt - i) {
        int sA = sortedSrc[s0 + i + eg];
        uint4 vA = gl8[(size_t)sA * 4 + sub];
        ACC4D(vA.x, a[0], a[1], a[2], a[3])
        ACC4D(vA.y, a[4], a[5], a[6], a[7])
        ACC4D(vA.z, a[8], a[9], a[10], a[11])
        ACC4D(vA.w, a[12], a[13], a[14], a[15])
    }
    // reduce over eg (lane bits 2,3)
#pragma unroll
    for (int j = 0; j < 16; j++) {
        a[j] += __shfl_xor(a[j], 4, 64);
        a[j] += __shfl_xor(a[j], 8, 64);
    }
    float dinv = 0x1p+120f / fmaxf((float)cnt, 1.0f);
    // self term (bf16) + bias
    uint4 r0 = grb[(size_t)node * 8 + sub * 2];
    uint4 r1 = grb[(size_t)node * 8 + sub * 2 + 1];
    float gr[16];
    gr[0] = bflo(r0.x); gr[1] = bfhi(r0.x); gr[2] = bflo(r0.y); gr[3] = bfhi(r0.y);
    gr[4] = bflo(r0.z); gr[5] = bfhi(r0.z); gr[6] = bflo(r0.w); gr[7] = bfhi(r0.w);
    gr[8] = bflo(r1.x); gr[9] = bfhi(r1.x); gr[10] = bflo(r1.y); gr[11] = bfhi(r1.y);
    gr[12] = bflo(r1.z); gr[13] = bfhi(r1.z); gr[14] = bflo(r1.w); gr[15] = bfhi(r1.w);
    float t[16];
    float ssq = 0.f;
#pragma unroll
    for (int q4 = 0; q4 < 4; q4++) {
        int col0 = sub * 16 + q4 * 4;
        float4 bq = (col0 < D_OUT) ? *(const float4*)(bias + col0)
                                   : (float4){0.f, 0.f, 0.f, 0.f};
        t[q4 * 4 + 0] = a[q4 * 4 + 0] * dinv + gr[q4 * 4 + 0] + bq.x;
        t[q4 * 4 + 1] = a[q4 * 4 + 1] * dinv + gr[q4 * 4 + 1] + bq.y;
        t[q4 * 4 + 2] = a[q4 * 4 + 2] * dinv + gr[q4 * 4 + 2] + bq.z;
        t[q4 * 4 + 3] = a[q4 * 4 + 3] * dinv + gr[q4 * 4 + 3] + bq.w;
    }
#pragma unroll
    for (int j = 0; j < 16; j++) ssq += t[j] * t[j];  // pad cols are exact zeros
    ssq += __shfl_xor(ssq, 1, 64);
    ssq += __shfl_xor(ssq, 2, 64);
    float inv = 1.0f / fmaxf(sqrtf(ssq), EPSN);
    float vv[16];
#pragma unroll
    for (int j = 0; j < 16; j++) vv[j] = t[j] * inv;
    int ncols = (sub < 2) ? 16 : ((sub == 2) ? 8 : 0);
    float m = -INFINITY;
    for (int j = 0; j < ncols; j++) m = fmaxf(m, vv[j]);
    m = fmaxf(m, __shfl_xor(m, 1, 64));
    m = fmaxf(m, __shfl_xor(m, 2, 64));
    float se = 0.f;
    for (int j = 0; j < ncols; j++) se += expf(vv[j] - m);
    se += __shfl_xor(se, 1, 64);
    se += __shfl_xor(se, 2, 64);
    float ls = logf(se) + m;
    if (eg == 0) {
#pragma unroll
        for (int q4 = 0; q4 < 4; q4++) {
            int col0 = sub * 16 + q4 * 4;
            if (col0 < D_OUT) {
                float4 o = (float4){vv[q4 * 4 + 0] - ls, vv[q4 * 4 + 1] - ls,
                                    vv[q4 * 4 + 2] - ls, vv[q4 * 4 + 3] - ls};
                *(float4*)(out + (size_t)node * D_OUT + col0) = o;
            }
        }
    }
}

static inline size_t align256(size_t x) { return (x + 255) & ~(size_t)255; }

extern "C" void kernel_launch(void* const* d_in, const int* in_sizes, int n_in,
                              void* d_out, int out_size, void* d_ws, size_t ws_size,
                              hipStream_t stream) {
    const float* x   = (const float*)d_in[0];
    const int*   ei  = (const int*)d_in[1];
    const float* Wl1 = (const float*)d_in[2];
    const float* bl1 = (const float*)d_in[3];
    const float* Wr1 = (const float*)d_in[4];
    const float* Wl2 = (const float*)d_in[5];
    const float* bl2 = (const float*)d_in[6];
    const float* Wr2 = (const float*)d_in[7];
    float* out = (float*)d_out;

    const int* src = ei;
    const int* dst = ei + N_EDGES;

    char* ws = (char*)d_ws;
    size_t off = 0;
    int* bucketCount = (int*)(ws + off); off += align256((size_t)NBUCK * 4);
    int* bucketStart = (int*)(ws + off); off += align256((size_t)(NBUCK + 1) * 4);
    int* cursor      = (int*)(ws + off); off += align256((size_t)NBUCK * 4);
    int* hist        = (int*)(ws + off); off += align256((size_t)N_NODES * 4);
    int* rowStart    = (int*)(ws + off); off += align256((size_t)N_NODES * 4);
    unsigned* pairs  = (unsigned*)(ws + off); off += align256((size_t)N_EDGES * 4);
    int* sortedSrc   = (int*)(ws + off); off += align256((size_t)N_EDGES * 4);
    unsigned* xb     = (unsigned*)(ws + off); off += align256((size_t)N_NODES * 128 * 2);
    unsigned* xs     = (unsigned*)(ws + off); off += align256((size_t)4 * N8 * 4);
    unsigned* meanb  = (unsigned*)(ws + off); off += align256((size_t)N_NODES * 128 * 2);
    unsigned char* g_l8 = (unsigned char*)(ws + off); off += align256((size_t)N_NODES * 64);
    unsigned short* g_r = (unsigned short*)(ws + off); off += align256((size_t)N_NODES * 64 * 2);
    unsigned short* bswz1 = (unsigned short*)(ws + off); off += align256((size_t)SWZ1_TOTAL * 2);
    unsigned short* bswz2 = (unsigned short*)(ws + off); off += align256((size_t)SWZ2_TOTAL * 2);

    hipMemsetAsync(bucketCount, 0, (size_t)NBUCK * 4, stream);

    prep_kernel<<<NPART + CASTB + F8B + SWZB, 256, 0, stream>>>(
        dst, bucketCount, x, xb, xs, Wl1, Wr1, Wl2, Wr2, bswz1, bswz2);
    bscan_kernel<<<1, 256, 0, stream>>>(bucketCount, bucketStart, cursor);
    bpart_kernel<<<PNPART, 512, 0, stream>>>(src, dst, cursor, pairs);
    csr_kernel<<<NBUCK, 256, 0, stream>>>(pairs, bucketStart, hist, rowStart, sortedSrc);

    for (int s = 0; s < 4; s++) {
        aggs_kernel<<<N_NODES / 4, 256, 0, stream>>>(
            xs + (size_t)s * N8, sortedSrc, rowStart, hist, (uint2*)meanb, s);
    }
    gemm1g_kernel<<<(N_NODES + 63) / 64, 256, 0, stream>>>(
        (const unsigned short*)meanb, (const unsigned short*)xb,
        (const short*)bswz1, bl1, (const short*)bswz2, g_l8, g_r);
    fused2f8_kernel<<<N_NODES / 16, 256, 0, stream>>>(
        (const uint4*)g_l8, (const uint4*)g_r, sortedSrc, rowStart, hist, bl2, out);
}

// Round 11
// 308.961 us; speedup vs baseline: 1.2393x; 1.2393x over previous
//
#include <hip/hip_runtime.h>
#include <math.h>

#define N_NODES 100000
#define N_EDGES 1600000
#define D_IN 128
#define HIDDEN 128
#define D_OUT 40
#define EPSN 1e-12f

#define NBUCK 391
#define EPB 4096
#define NPART ((N_EDGES + EPB - 1) / EPB)    // 391
#define PEPB 16384
#define PNPART ((N_EDGES + PEPB - 1) / PEPB) // 98

#define SWZ1_TOTAL (8 * 8 * 4 * 16 * 8)   // 32768
#define SWZ2_TOTAL (4 * 8 * 4 * 16 * 8)   // 16384
#define CASTB ((N_NODES * 16) / 256)      // 6250: fp32 -> bf16 rows
#define F8B ((N_NODES * 32) / 256)        // 12500: fp32 -> fp8 rows
#define SWZB ((SWZ1_TOTAL + SWZ2_TOTAL + 255) / 256)

typedef __attribute__((ext_vector_type(8))) short short8;
typedef __attribute__((ext_vector_type(4))) float float4v;
typedef __attribute__((ext_vector_type(2))) float float2v;

static __device__ inline unsigned short f2bf(float f) {
    union { float f; unsigned u; } v; v.f = f;
    unsigned r = v.u + 0x7fffu + ((v.u >> 16) & 1u);
    return (unsigned short)(r >> 16);
}
static __device__ inline float bflo(unsigned u) {
    union { unsigned u; float f; } v; v.u = u << 16;
    return v.f;
}
static __device__ inline float bfhi(unsigned u) {
    union { unsigned u; float f; } v; v.u = u & 0xffff0000u;
    return v.f;
}

// ---------- fp8 e4m3 encode/decode: HW cvt when available, bit-trick fallback ----------
#if defined(__has_builtin)
#if __has_builtin(__builtin_amdgcn_cvt_pk_f32_fp8) && __has_builtin(__builtin_amdgcn_cvt_pk_fp8_f32)
#define HAVE_HW_FP8 1
#endif
#endif

static __device__ inline float2v fp8lo(unsigned u) {
#ifdef HAVE_HW_FP8
    return __builtin_amdgcn_cvt_pk_f32_fp8(u, false);
#else
    unsigned b0 = u & 0xffu, b1 = (u >> 8) & 0xffu;
    union { unsigned u; float f; } v0, v1;
    v0.u = ((b0 & 0x80u) << 24) | ((b0 & 0x7fu) << 20);
    v1.u = ((b1 & 0x80u) << 24) | ((b1 & 0x7fu) << 20);
    float2v r; r.x = v0.f * 0x1p+120f; r.y = v1.f * 0x1p+120f;
    return r;
#endif
}
static __device__ inline float2v fp8hi(unsigned u) {
#ifdef HAVE_HW_FP8
    return __builtin_amdgcn_cvt_pk_f32_fp8(u, true);
#else
    unsigned b0 = (u >> 16) & 0xffu, b1 = (u >> 24) & 0xffu;
    union { unsigned u; float f; } v0, v1;
    v0.u = ((b0 & 0x80u) << 24) | ((b0 & 0x7fu) << 20);
    v1.u = ((b1 & 0x80u) << 24) | ((b1 & 0x7fu) << 20);
    float2v r; r.x = v0.f * 0x1p+120f; r.y = v1.f * 0x1p+120f;
    return r;
#endif
}
static __device__ inline unsigned enc1(float x) {
    union { float f; unsigned u; } v; v.f = x * 0x1p-120f;
    unsigned um = v.u & 0x7fffffffu;
    unsigned r = um + 0x7FFFFu + ((um >> 20) & 1u);
    return ((r >> 20) & 0x7fu) | ((v.u >> 24) & 0x80u);
}
static __device__ inline unsigned fp8pack(float f0, float f1, float f2, float f3) {
#ifdef HAVE_HW_FP8
    unsigned u = __builtin_amdgcn_cvt_pk_fp8_f32(f0, f1, 0u, false);
    u = __builtin_amdgcn_cvt_pk_fp8_f32(f2, f3, u, true);
    return u;
#else
    return enc1(f0) | (enc1(f1) << 8) | (enc1(f2) << 16) | (enc1(f3) << 24);
#endif
}
static __device__ inline unsigned char encf8b(float x) {
#ifdef HAVE_HW_FP8
    return (unsigned char)(__builtin_amdgcn_cvt_pk_fp8_f32(x, 0.0f, 0u, false) & 0xffu);
#else
    return (unsigned char)enc1(x);
#endif
}

// accumulate 4 fp8 (one dword) into 4 fp32
#define ACC1D(U, A0, A1, A2, A3)                                     \
    { float2v pl_ = fp8lo(U), ph_ = fp8hi(U);                        \
      A0 += pl_.x; A1 += pl_.y; A2 += ph_.x; A3 += ph_.y; }

// ---------------- prep: bhist + bf16 cast + fp8 cast + weight swizzles ----------------
__global__ void prep_kernel(const int* __restrict__ dst, int* __restrict__ bucketCount,
                            const float* __restrict__ x, unsigned* __restrict__ xb,
                            unsigned* __restrict__ xf8,
                            const float* __restrict__ Wl1, const float* __restrict__ Wr1,
                            const float* __restrict__ Wl2, const float* __restrict__ Wr2,
                            unsigned short* __restrict__ out1, unsigned short* __restrict__ out2) {
    __shared__ int h[NBUCK];
    int b = blockIdx.x, t = threadIdx.x;
    if (b < NPART) {
        for (int i = t; i < NBUCK; i += 256) h[i] = 0;
        __syncthreads();
        int es = b * EPB;
        int ee = min(es + EPB, N_EDGES);
        for (int i = es + t; i < ee; i += 256) atomicAdd(&h[dst[i] >> 8], 1);
        __syncthreads();
        for (int i = t; i < NBUCK; i += 256)
            if (h[i]) atomicAdd(&bucketCount[i], h[i]);
        return;
    }
    b -= NPART;
    if (b < CASTB) {
        int g = b * 256 + t;
        const float4* x4 = (const float4*)x;
        float4 lo = x4[2 * g], hi = x4[2 * g + 1];
        uint4 o;
        o.x = (unsigned)f2bf(lo.x) | ((unsigned)f2bf(lo.y) << 16);
        o.y = (unsigned)f2bf(lo.z) | ((unsigned)f2bf(lo.w) << 16);
        o.z = (unsigned)f2bf(hi.x) | ((unsigned)f2bf(hi.y) << 16);
        o.w = (unsigned)f2bf(hi.z) | ((unsigned)f2bf(hi.w) << 16);
        ((uint4*)xb)[g] = o;
        return;
    }
    b -= CASTB;
    if (b < F8B) {
        int g = b * 256 + t;
        float4 f = ((const float4*)x)[g];
        xf8[g] = fp8pack(f.x, f.y, f.z, f.w);
        return;
    }
    b -= F8B;
    {
        int idx = b * 256 + t;
        if (idx < SWZ1_TOTAL) {
            int j = idx & 7, l15 = (idx >> 3) & 15, quad = (idx >> 7) & 3;
            int rem = idx >> 9;
            int c = rem & 7, kt = rem >> 3;
            int k = kt * 32 + quad * 8 + j;
            int n = c * 16 + l15;
            float val = (k < 128) ? Wl1[k * HIDDEN + n] : Wr1[(k - 128) * HIDDEN + n];
            out1[idx] = f2bf(val);
        } else if (idx < SWZ1_TOTAL + SWZ2_TOTAL) {
            idx -= SWZ1_TOTAL;
            int j = idx & 7, l15 = (idx >> 3) & 15, quad = (idx >> 7) & 3;
            int rem = idx >> 9;
            int c = rem & 7, kt = rem >> 3;
            int k = kt * 32 + quad * 8 + j;
            int n = c * 16 + l15;
            float val = 0.0f;
            if (n < D_OUT) val = Wl2[k * D_OUT + n];
            else if (n >= 64 && n < 64 + D_OUT) val = Wr2[k * D_OUT + (n - 64)];
            out2[idx] = f2bf(val);
        }
    }
}

// ---------------- scan 391 bucket counts ----------------
__global__ void bscan_kernel(const int* __restrict__ bc, int* __restrict__ bstart,
                             int* __restrict__ cursor) {
    __shared__ int s[256];
    int t = threadIdx.x;
    int a = (2 * t < NBUCK) ? bc[2 * t] : 0;
    int b = (2 * t + 1 < NBUCK) ? bc[2 * t + 1] : 0;
    int tp = a + b;
    s[t] = tp;
    __syncthreads();
    for (int off = 1; off < 256; off <<= 1) {
        int tmp = (t >= off) ? s[t - off] : 0;
        __syncthreads();
        s[t] += tmp;
        __syncthreads();
    }
    int texcl = s[t] - tp;
    if (2 * t < NBUCK) { bstart[2 * t] = texcl; cursor[2 * t] = texcl; }
    if (2 * t + 1 < NBUCK) { bstart[2 * t + 1] = texcl + a; cursor[2 * t + 1] = texcl + a; }
    if (t == 255) bstart[NBUCK] = s[255];
}

// ---------------- partition edges into buckets ----------------
__global__ __launch_bounds__(512) void bpart_kernel(
    const int* __restrict__ src, const int* __restrict__ dst,
    int* __restrict__ cursor, unsigned* __restrict__ pairs) {
    __shared__ int h[NBUCK];
    __shared__ int base[NBUCK];
    int t = threadIdx.x;
    for (int i = t; i < NBUCK; i += 512) h[i] = 0;
    __syncthreads();
    int es = blockIdx.x * PEPB;
    int ee = min(es + PEPB, N_EDGES);
    for (int i = es + t; i < ee; i += 512) atomicAdd(&h[dst[i] >> 8], 1);
    __syncthreads();
    for (int i = t; i < NBUCK; i += 512) {
        int c = h[i];
        base[i] = c ? atomicAdd(&cursor[i], c) : 0;
    }
    __syncthreads();
    for (int i = t; i < NBUCK; i += 512) h[i] = 0;
    __syncthreads();
    for (int i = es + t; i < ee; i += 512) {
        int d = dst[i];
        int bk = d >> 8;
        int r = atomicAdd(&h[bk], 1);
        pairs[base[bk] + r] = ((unsigned)src[i] << 8) | (unsigned)(d & 255);
    }
}

// ---------------- per-bucket CSR finalize ----------------
__global__ void csr_kernel(const unsigned* __restrict__ pairs, const int* __restrict__ bstart,
                           int* __restrict__ hist, int* __restrict__ rowStart,
                           int* __restrict__ sortedSrc) {
    __shared__ int cnt[256];
    __shared__ int sc[256];
    __shared__ int cur[256];
    int b = blockIdx.x, t = threadIdx.x;
    int es = bstart[b], ee = bstart[b + 1];
    cnt[t] = 0;
    __syncthreads();
    for (int i = es + t; i < ee; i += 256) atomicAdd(&cnt[pairs[i] & 255], 1);
    __syncthreads();
    int v = cnt[t];
    sc[t] = v;
    __syncthreads();
    for (int off = 1; off < 256; off <<= 1) {
        int tmp = (t >= off) ? sc[t - off] : 0;
        __syncthreads();
        sc[t] += tmp;
        __syncthreads();
    }
    int excl = sc[t] - v;
    int node = (b << 8) + t;
    if (node < N_NODES) {
        hist[node] = v;
        rowStart[node] = es + excl;
    }
    cur[t] = excl;
    __syncthreads();
    for (int i = es + t; i < ee; i += 256) {
        unsigned p = pairs[i];
        int r = atomicAdd(&cur[p & 255], 1);
        sortedSrc[es + r] = (int)(p >> 8);
    }
}

// ---------------- layer-1 gather-mean from fp8 rows: one wave per node ----------------
// 8 lanes (sl) x 16B cover the 128B fp8 row; 8 edge-groups (q); 16 accumulators/lane.
#define ACC4(v)                              \
    ACC1D(v.x, a[0], a[1], a[2], a[3])       \
    ACC1D(v.y, a[4], a[5], a[6], a[7])       \
    ACC1D(v.z, a[8], a[9], a[10], a[11])     \
    ACC1D(v.w, a[12], a[13], a[14], a[15])

__global__ void agg_kernel(const uint4* __restrict__ xf8,  // [N][8] uint4 (128B fp8 rows)
                           const int* __restrict__ sortedSrc,
                           const int* __restrict__ rowStart, const int* __restrict__ hist,
                           uint4* __restrict__ meanb) {
    int w = __builtin_amdgcn_readfirstlane((int)(threadIdx.x >> 6));
    int node = blockIdx.x * 4 + w;
    int lane = threadIdx.x & 63;
    int q = lane >> 3, sl = lane & 7;
    int s0 = __builtin_amdgcn_readfirstlane(rowStart[node]);
    int cnt = __builtin_amdgcn_readfirstlane(hist[node]);
    float a[16];
#pragma unroll
    for (int e = 0; e < 16; e++) a[e] = 0.f;
    int i = 0;
    for (; i + 16 <= cnt; i += 16) {
        int sA = sortedSrc[s0 + i + q];
        int sB = sortedSrc[s0 + i + 8 + q];
        uint4 vA = xf8[(size_t)sA * 8 + sl];
        uint4 vB = xf8[(size_t)sB * 8 + sl];
        ACC4(vA)
        ACC4(vB)
    }
    for (; i + 8 <= cnt; i += 8) {
        int s = sortedSrc[s0 + i + q];
        uint4 v = xf8[(size_t)s * 8 + sl];
        ACC4(v)
    }
    if (q < cnt - i) {
        int s = sortedSrc[s0 + i + q];
        uint4 v = xf8[(size_t)s * 8 + sl];
        ACC4(v)
    }
#pragma unroll
    for (int e = 0; e < 16; e++) {
        a[e] += __shfl_xor(a[e], 8, 64);
        a[e] += __shfl_xor(a[e], 16, 64);
        a[e] += __shfl_xor(a[e], 32, 64);
    }
    if (q == 0) {
        float dinv = 1.0f / fmaxf((float)cnt, 1.0f);
        uint4 o1, o2;
        o1.x = (unsigned)f2bf(a[0] * dinv)  | ((unsigned)f2bf(a[1] * dinv) << 16);
        o1.y = (unsigned)f2bf(a[2] * dinv)  | ((unsigned)f2bf(a[3] * dinv) << 16);
        o1.z = (unsigned)f2bf(a[4] * dinv)  | ((unsigned)f2bf(a[5] * dinv) << 16);
        o1.w = (unsigned)f2bf(a[6] * dinv)  | ((unsigned)f2bf(a[7] * dinv) << 16);
        o2.x = (unsigned)f2bf(a[8] * dinv)  | ((unsigned)f2bf(a[9] * dinv) << 16);
        o2.y = (unsigned)f2bf(a[10] * dinv) | ((unsigned)f2bf(a[11] * dinv) << 16);
        o2.z = (unsigned)f2bf(a[12] * dinv) | ((unsigned)f2bf(a[13] * dinv) << 16);
        o2.w = (unsigned)f2bf(a[14] * dinv) | ((unsigned)f2bf(a[15] * dinv) << 16);
        meanb[(size_t)node * 16 + sl * 2] = o1;
        meanb[(size_t)node * 16 + sl * 2 + 1] = o2;
    }
}

// ---------------- layer-1 GEMM + norm + relu + layer-2 projection ----------------
__global__ __launch_bounds__(256) void gemm1g_kernel(
    const unsigned short* __restrict__ meanb, const unsigned short* __restrict__ xb,
    const short* __restrict__ bswz1, const float* __restrict__ bias1,
    const short* __restrict__ bswz2,
    unsigned char* __restrict__ g_l8, unsigned short* __restrict__ g_r) {
    __shared__ unsigned short hT[4][16][140];
    int tid = threadIdx.x;
    int w = __builtin_amdgcn_readfirstlane(tid >> 6);
    int lane = tid & 63;
    int l15 = lane & 15, quad = lane >> 4;
    int n0 = blockIdx.x * 64;
    int nodeA = n0 + w * 16 + l15;
    if (nodeA >= N_NODES) nodeA = N_NODES - 1;

    float4v acc[8];
#pragma unroll
    for (int c = 0; c < 8; c++) acc[c] = (float4v){0.f, 0.f, 0.f, 0.f};
#pragma unroll
    for (int kt = 0; kt < 8; kt++) {
        const unsigned short* ab = (kt < 4) ? meanb : xb;
        short8 a = *(const short8*)(ab + (size_t)nodeA * 128 + (kt & 3) * 32 + quad * 8);
#pragma unroll
        for (int c = 0; c < 8; c++) {
            short8 b = *(const short8*)(bswz1 + (((kt * 8 + c) * 4 + quad) * 16 + l15) * 8);
            acc[c] = __builtin_amdgcn_mfma_f32_16x16x32_bf16(a, b, acc[c], 0, 0, 0);
        }
    }

    float v[8][4];
    float ss[4] = {0.f, 0.f, 0.f, 0.f};
#pragma unroll
    for (int c = 0; c < 8; c++) {
        float bi = bias1[c * 16 + l15];
#pragma unroll
        for (int r = 0; r < 4; r++) {
            float t = acc[c][r] + bi;
            v[c][r] = t;
            ss[r] += t * t;
        }
    }
#pragma unroll
    for (int r = 0; r < 4; r++)
        for (int off = 1; off < 16; off <<= 1) ss[r] += __shfl_xor(ss[r], off, 64);
#pragma unroll
    for (int r = 0; r < 4; r++) {
        float inv = 1.0f / fmaxf(sqrtf(ss[r]), EPSN);
#pragma unroll
        for (int c = 0; c < 8; c++) {
            hT[w][quad * 4 + r][c * 16 + l15] = f2bf(fmaxf(v[c][r] * inv, 0.0f));
        }
    }

    float4v acc2[8];
#pragma unroll
    for (int c = 0; c < 8; c++) acc2[c] = (float4v){0.f, 0.f, 0.f, 0.f};
#pragma unroll
    for (int kt = 0; kt < 4; kt++) {
        short8 a = *(const short8*)&hT[w][l15][kt * 32 + quad * 8];
#pragma unroll
        for (int c = 0; c < 8; c++) {
            short8 b = *(const short8*)(bswz2 + (((kt * 8 + c) * 4 + quad) * 16 + l15) * 8);
            acc2[c] = __builtin_amdgcn_mfma_f32_16x16x32_bf16(a, b, acc2[c], 0, 0, 0);
        }
    }
#pragma unroll
    for (int r = 0; r < 4; r++) {
        int node = n0 + w * 16 + quad * 4 + r;
        if (node < N_NODES) {
#pragma unroll
            for (int c = 0; c < 4; c++)
                g_l8[(size_t)node * 64 + c * 16 + l15] = encf8b(acc2[c][r]);
#pragma unroll
            for (int c = 4; c < 8; c++)
                g_r[(size_t)node * 64 + (c - 4) * 16 + l15] = f2bf(acc2[c][r]);
        }
    }
}

// ---------------- layer 2 final: 4 nodes/wave, fp8 g_l gather (64B rows), HW cvt ----------------
// Lane: g = lane>>4 (node), eg = (lane>>2)&3 (edge group), sub = lane&3 (16B of row).
__global__ void fused2f8_kernel(const uint4* __restrict__ gl8, const uint4* __restrict__ grb,
                                const int* __restrict__ sortedSrc,
                                const int* __restrict__ rowStart, const int* __restrict__ hist,
                                const float* __restrict__ bias, float* __restrict__ out) {
    int tid = threadIdx.x;
    int w = __builtin_amdgcn_readfirstlane(tid >> 6);
    int lane = tid & 63;
    int g = lane >> 4, eg = (lane >> 2) & 3, sub = lane & 3;
    int node = blockIdx.x * 16 + w * 4 + g;
    int s0 = rowStart[node];
    int cnt = hist[node];
    float a[16];
#pragma unroll
    for (int j = 0; j < 16; j++) a[j] = 0.f;
    int i = 0;
    for (; i + 8 <= cnt; i += 8) {
        int sA = sortedSrc[s0 + i + eg];
        int sB = sortedSrc[s0 + i + 4 + eg];
        uint4 vA = gl8[(size_t)sA * 4 + sub];
        uint4 vB = gl8[(size_t)sB * 4 + sub];
        ACC4(vA)
        ACC4(vB)
    }
    if (i + eg < cnt) {
        int sA = sortedSrc[s0 + i + eg];
        uint4 vA = gl8[(size_t)sA * 4 + sub];
        ACC4(vA)
    }
    i += 4;
    if (i + eg < cnt) {
        int sA = sortedSrc[s0 + i + eg];
        uint4 vA = gl8[(size_t)sA * 4 + sub];
        ACC4(vA)
    }
    // reduce over eg (lane bits 2,3)
#pragma unroll
    for (int j = 0; j < 16; j++) {
        a[j] += __shfl_xor(a[j], 4, 64);
        a[j] += __shfl_xor(a[j], 8, 64);
    }
    float dinv = 1.0f / fmaxf((float)cnt, 1.0f);
    // self term (bf16) + bias
    uint4 r0 = grb[(size_t)node * 8 + sub * 2];
    uint4 r1 = grb[(size_t)node * 8 + sub * 2 + 1];
    float gr[16];
    gr[0] = bflo(r0.x); gr[1] = bfhi(r0.x); gr[2] = bflo(r0.y); gr[3] = bfhi(r0.y);
    gr[4] = bflo(r0.z); gr[5] = bfhi(r0.z); gr[6] = bflo(r0.w); gr[7] = bfhi(r0.w);
    gr[8] = bflo(r1.x); gr[9] = bfhi(r1.x); gr[10] = bflo(r1.y); gr[11] = bfhi(r1.y);
    gr[12] = bflo(r1.z); gr[13] = bfhi(r1.z); gr[14] = bflo(r1.w); gr[15] = bfhi(r1.w);
    float t[16];
    float ssq = 0.f;
#pragma unroll
    for (int q4 = 0; q4 < 4; q4++) {
        int col0 = sub * 16 + q4 * 4;
        float4 bq = (col0 < D_OUT) ? *(const float4*)(bias + col0)
                                   : (float4){0.f, 0.f, 0.f, 0.f};
        t[q4 * 4 + 0] = a[q4 * 4 + 0] * dinv + gr[q4 * 4 + 0] + bq.x;
        t[q4 * 4 + 1] = a[q4 * 4 + 1] * dinv + gr[q4 * 4 + 1] + bq.y;
        t[q4 * 4 + 2] = a[q4 * 4 + 2] * dinv + gr[q4 * 4 + 2] + bq.z;
        t[q4 * 4 + 3] = a[q4 * 4 + 3] * dinv + gr[q4 * 4 + 3] + bq.w;
    }
#pragma unroll
    for (int j = 0; j < 16; j++) ssq += t[j] * t[j];  // pad cols are exact zeros
    ssq += __shfl_xor(ssq, 1, 64);
    ssq += __shfl_xor(ssq, 2, 64);
    float inv = 1.0f / fmaxf(sqrtf(ssq), EPSN);
    float vv[16];
#pragma unroll
    for (int j = 0; j < 16; j++) vv[j] = t[j] * inv;
    int ncols = (sub < 2) ? 16 : ((sub == 2) ? 8 : 0);
    float m = -INFINITY;
    for (int j = 0; j < ncols; j++) m = fmaxf(m, vv[j]);
    m = fmaxf(m, __shfl_xor(m, 1, 64));
    m = fmaxf(m, __shfl_xor(m, 2, 64));
    float se = 0.f;
    for (int j = 0; j < ncols; j++) se += expf(vv[j] - m);
    se += __shfl_xor(se, 1, 64);
    se += __shfl_xor(se, 2, 64);
    float ls = logf(se) + m;
    if (eg == 0) {
#pragma unroll
        for (int q4 = 0; q4 < 4; q4++) {
            int col0 = sub * 16 + q4 * 4;
            if (col0 < D_OUT) {
                float4 o = (float4){vv[q4 * 4 + 0] - ls, vv[q4 * 4 + 1] - ls,
                                    vv[q4 * 4 + 2] - ls, vv[q4 * 4 + 3] - ls};
                *(float4*)(out + (size_t)node * D_OUT + col0) = o;
            }
        }
    }
}

static inline size_t align256(size_t x) { return (x + 255) & ~(size_t)255; }

extern "C" void kernel_launch(void* const* d_in, const int* in_sizes, int n_in,
                              void* d_out, int out_size, void* d_ws, size_t ws_size,
                              hipStream_t stream) {
    const float* x   = (const float*)d_in[0];
    const int*   ei  = (const int*)d_in[1];
    const float* Wl1 = (const float*)d_in[2];
    const float* bl1 = (const float*)d_in[3];
    const float* Wr1 = (const float*)d_in[4];
    const float* Wl2 = (const float*)d_in[5];
    const float* bl2 = (const float*)d_in[6];
    const float* Wr2 = (const float*)d_in[7];
    float* out = (float*)d_out;

    const int* src = ei;
    const int* dst = ei + N_EDGES;

    char* ws = (char*)d_ws;
    size_t off = 0;
    int* bucketCount = (int*)(ws + off); off += align256((size_t)NBUCK * 4);
    int* bucketStart = (int*)(ws + off); off += align256((size_t)(NBUCK + 1) * 4);
    int* cursor      = (int*)(ws + off); off += align256((size_t)NBUCK * 4);
    int* hist        = (int*)(ws + off); off += align256((size_t)N_NODES * 4);
    int* rowStart    = (int*)(ws + off); off += align256((size_t)N_NODES * 4);
    unsigned* pairs  = (unsigned*)(ws + off); off += align256((size_t)N_EDGES * 4);
    int* sortedSrc   = (int*)(ws + off); off += align256((size_t)N_EDGES * 4);
    unsigned* xb     = (unsigned*)(ws + off); off += align256((size_t)N_NODES * 128 * 2);
    unsigned* xf8    = (unsigned*)(ws + off); off += align256((size_t)N_NODES * 128);
    unsigned* meanb  = (unsigned*)(ws + off); off += align256((size_t)N_NODES * 128 * 2);
    unsigned char* g_l8 = (unsigned char*)(ws + off); off += align256((size_t)N_NODES * 64);
    unsigned short* g_r = (unsigned short*)(ws + off); off += align256((size_t)N_NODES * 64 * 2);
    unsigned short* bswz1 = (unsigned short*)(ws + off); off += align256((size_t)SWZ1_TOTAL * 2);
    unsigned short* bswz2 = (unsigned short*)(ws + off); off += align256((size_t)SWZ2_TOTAL * 2);

    hipMemsetAsync(bucketCount, 0, (size_t)NBUCK * 4, stream);

    prep_kernel<<<NPART + CASTB + F8B + SWZB, 256, 0, stream>>>(
        dst, bucketCount, x, xb, xf8, Wl1, Wr1, Wl2, Wr2, bswz1, bswz2);
    bscan_kernel<<<1, 256, 0, stream>>>(bucketCount, bucketStart, cursor);
    bpart_kernel<<<PNPART, 512, 0, stream>>>(src, dst, cursor, pairs);
    csr_kernel<<<NBUCK, 256, 0, stream>>>(pairs, bucketStart, hist, rowStart, sortedSrc);

    agg_kernel<<<N_NODES / 4, 256, 0, stream>>>((const uint4*)xf8, sortedSrc, rowStart, hist,
                                                (uint4*)meanb);
    gemm1g_kernel<<<(N_NODES + 63) / 64, 256, 0, stream>>>(
        (const unsigned short*)meanb, (const unsigned short*)xb,
        (const short*)bswz1, bl1, (const short*)bswz2, g_l8, g_r);
    fused2f8_kernel<<<N_NODES / 16, 256, 0, stream>>>(
        (const uint4*)g_l8, (const uint4*)g_r, sortedSrc, rowStart, hist, bl2, out);
}